// Round 1
// baseline (283.115 us; speedup 1.0000x reference)
//
#include <hip/hip_runtime.h>

// ---------------------------------------------------------------------------
// LSTM (Alex Graves) single step, batch 8192.
//   A = [H | x[:,n,:]]  (8192 x 768)  fp16-packed
//   W = [fg;ig;in;og] x [w_h|w_x]  (2048 x 768) fp16-packed
//   Z = A @ W^T  (8192 x 2048) fp32   -- MFMA 16x16x32 f16
//   epilogue: gates -> cm, h
// ---------------------------------------------------------------------------

typedef _Float16 half8 __attribute__((ext_vector_type(8)));
typedef _Float16 half4v __attribute__((ext_vector_type(4)));
typedef float floatx4 __attribute__((ext_vector_type(4)));

#define BATCH 8192
#define NSTEPS 16
#define IN_F 256
#define OUT_F 512
#define KDIM 768    // OUT_F + IN_F
#define NDIM 2048   // 4 * OUT_F

#define BM 128
#define BN 128
#define BK 64

__device__ __forceinline__ void async_copy16(const void* gptr, void* lptr) {
  __builtin_amdgcn_global_load_lds(
      (const __attribute__((address_space(1))) unsigned int*)gptr,
      (__attribute__((address_space(3))) unsigned int*)lptr,
      16, 0, 0);
}

__device__ __forceinline__ float sigmoidf_(float x) {
  // safe for large |x|: exp(+inf) -> 1/(1+inf)=0 ; exp(-inf) -> 1/(1+0)=1
  return 1.0f / (1.0f + __expf(-x));
}

__device__ __forceinline__ float tanhf_(float x) {
  // clamp: pre-activations can reach |x|~150; __expf(300) = inf -> NaN
  x = fminf(fmaxf(x, -20.0f), 20.0f);
  float e = __expf(2.0f * x);
  return (e - 1.0f) / (e + 1.0f);
}

// --------------------------- pack A = [H | x_n] ----------------------------
// grid: 8192 blocks x 192 threads, 4 halves per thread
__global__ void pack_A(const float* __restrict__ H, const float* __restrict__ x,
                       const int* __restrict__ nptr, _Float16* __restrict__ A) {
  const int n = *nptr;
  const int b = blockIdx.x;
  const int k = threadIdx.x * 4;
  float4 v;
  if (k < OUT_F)
    v = *(const float4*)(H + (size_t)b * OUT_F + k);
  else
    v = *(const float4*)(x + ((size_t)b * NSTEPS + n) * IN_F + (k - OUT_F));
  half4v h = {(_Float16)v.x, (_Float16)v.y, (_Float16)v.z, (_Float16)v.w};
  *(half4v*)(A + (size_t)b * KDIM + k) = h;
}

// ------------------------ pack W (2048 x 768 fp16) -------------------------
// row = g*512 + j, g in {fg,ig,in,og}; cols [0,512)=w_h row j, [512,768)=w_x
// grid: 2048 blocks x 192 threads
__global__ void pack_W(const float* __restrict__ fg_w_h, const float* __restrict__ fg_w_x,
                       const float* __restrict__ ig_w_h, const float* __restrict__ ig_w_x,
                       const float* __restrict__ in_w_h, const float* __restrict__ in_w_x,
                       const float* __restrict__ og_w_h, const float* __restrict__ og_w_x,
                       _Float16* __restrict__ W) {
  const int row = blockIdx.x;
  const int g = row >> 9;
  const int j = row & 511;
  const int k = threadIdx.x * 4;
  const float* src;
  if (k < OUT_F) {
    const float* wh = (g == 0) ? fg_w_h : (g == 1) ? ig_w_h : (g == 2) ? in_w_h : og_w_h;
    src = wh + (size_t)j * OUT_F + k;
  } else {
    const float* wx = (g == 0) ? fg_w_x : (g == 1) ? ig_w_x : (g == 2) ? in_w_x : og_w_x;
    src = wx + (size_t)j * IN_F + (k - OUT_F);
  }
  float4 v = *(const float4*)src;
  half4v h = {(_Float16)v.x, (_Float16)v.y, (_Float16)v.z, (_Float16)v.w};
  *(half4v*)(W + (size_t)row * KDIM + k) = h;
}

// ------------------------------- GEMM --------------------------------------
// Z[m][nn] = sum_k A[m][k] * W[nn][k]
// 128x128 tile, BK=64, 256 thr / 4 waves, each wave 64x64 (4x4 MFMA tiles).
// LDS layout in 16B granules: slot(row, c_lds) = row*8 + c_lds, holding global
// chunk c_glb = c_lds ^ (row&7). The XOR is applied on the GLOBAL address at
// staging time so global_load_lds's wave-uniform-base+lane*16 rule is kept,
// and ds_read_b128 fragment reads become 2-way (free) instead of 16-way.
__global__ __launch_bounds__(256) void gemm_f16(const _Float16* __restrict__ A,
                                                const _Float16* __restrict__ W,
                                                float* __restrict__ Z) {
  __shared__ __align__(16) _Float16 As[BM * BK];
  __shared__ __align__(16) _Float16 Bs[BN * BK];

  const int tid = threadIdx.x;
  const int lane = tid & 63;
  const int wave = tid >> 6;
  const int quad = lane >> 4;
  const int l16 = lane & 15;
  const int m0 = blockIdx.y * BM;
  const int n0 = blockIdx.x * BN;
  const int mw = (wave >> 1) * 64;
  const int nw = (wave & 1) * 64;

  floatx4 acc[4][4] = {};

  for (int kt = 0; kt < KDIM; kt += BK) {
    __syncthreads();  // previous compute done before LDS overwrite
#pragma unroll
    for (int r = 0; r < 4; ++r) {
      const int g = r * 256 + tid;       // granule index, 16B each
      const int row = g >> 3;
      const int cl = g & 7;
      const int cg = cl ^ (row & 7);     // swizzled global chunk
      async_copy16(A + (size_t)(m0 + row) * KDIM + kt + cg * 8,
                   (_Float16*)As + g * 8);
      async_copy16(W + (size_t)(n0 + row) * KDIM + kt + cg * 8,
                   (_Float16*)Bs + g * 8);
    }
    __syncthreads();  // compiler drains vmcnt before s_barrier

#pragma unroll
    for (int ks = 0; ks < 2; ++ks) {     // two k-steps of 32 within BK=64
      half8 af[4], bf[4];
#pragma unroll
      for (int i = 0; i < 4; ++i) {
        const int row = mw + i * 16 + l16;
        const int chunk = ks * 4 + quad;  // 16B chunk within the row
        const int gran = row * 8 + (chunk ^ (row & 7));
        af[i] = *(const half8*)(As + gran * 8);
      }
#pragma unroll
      for (int j = 0; j < 4; ++j) {
        const int row = nw + j * 16 + l16;
        const int chunk = ks * 4 + quad;
        const int gran = row * 8 + (chunk ^ (row & 7));
        bf[j] = *(const half8*)(Bs + gran * 8);
      }
#pragma unroll
      for (int i = 0; i < 4; ++i)
#pragma unroll
        for (int j = 0; j < 4; ++j)
          acc[i][j] = __builtin_amdgcn_mfma_f32_16x16x32_f16(af[i], bf[j], acc[i][j], 0, 0, 0);
    }
  }

  // C/D layout: col = lane&15, row = (lane>>4)*4 + reg   (m89/m91-verified)
#pragma unroll
  for (int i = 0; i < 4; ++i) {
    const int rbase = m0 + mw + i * 16 + quad * 4;
#pragma unroll
    for (int j = 0; j < 4; ++j) {
      const int col = n0 + nw + j * 16 + l16;
#pragma unroll
      for (int r = 0; r < 4; ++r)
        Z[(size_t)(rbase + r) * NDIM + col] = acc[i][j][r];
    }
  }
}

// ----------------------------- epilogue ------------------------------------
// per (b, j): fg,ig,inn,og from Z cols j, 512+j, 1024+j, 1536+j
// grid: 4096 blocks x 256 threads, 4 j's per thread (float4)
__global__ void epilogue(const float* __restrict__ Z, const float* __restrict__ C,
                         const float* __restrict__ fg_w_c, const float* __restrict__ fg_b,
                         const float* __restrict__ ig_w_c, const float* __restrict__ ig_b,
                         const float* __restrict__ in_b,
                         const float* __restrict__ og_w_cn, const float* __restrict__ og_b,
                         float* __restrict__ out) {
  const int t = blockIdx.x * 256 + threadIdx.x;
  const int j = (t & 127) << 2;
  const int b = t >> 7;

  const float4 zf = *(const float4*)(Z + (size_t)b * NDIM + j);
  const float4 zi = *(const float4*)(Z + (size_t)b * NDIM + OUT_F + j);
  const float4 zn = *(const float4*)(Z + (size_t)b * NDIM + 2 * OUT_F + j);
  const float4 zo = *(const float4*)(Z + (size_t)b * NDIM + 3 * OUT_F + j);
  const float4 cv = *(const float4*)(C + (size_t)b * OUT_F + j);
  const float4 fwc = *(const float4*)(fg_w_c + j);
  const float4 fb  = *(const float4*)(fg_b + j);
  const float4 iwc = *(const float4*)(ig_w_c + j);
  const float4 ib  = *(const float4*)(ig_b + j);
  const float4 nb  = *(const float4*)(in_b + j);
  const float4 owc = *(const float4*)(og_w_cn + j);
  const float4 ob  = *(const float4*)(og_b + j);

  const float* zfp = (const float*)&zf; const float* zip = (const float*)&zi;
  const float* znp = (const float*)&zn; const float* zop = (const float*)&zo;
  const float* cp  = (const float*)&cv;
  const float* fwcp = (const float*)&fwc; const float* fbp = (const float*)&fb;
  const float* iwcp = (const float*)&iwc; const float* ibp = (const float*)&ib;
  const float* nbp  = (const float*)&nb;
  const float* owcp = (const float*)&owc; const float* obp = (const float*)&ob;

  float4 cm4, h4;
  float* cmp = (float*)&cm4;
  float* hp  = (float*)&h4;
#pragma unroll
  for (int q = 0; q < 4; ++q) {
    const float c = cp[q];
    const float fg = sigmoidf_(fwcp[q] * c + zfp[q] + fbp[q]);
    const float ig = sigmoidf_(iwcp[q] * c + zip[q] + ibp[q]);
    const float inn = tanhf_(znp[q] + nbp[q]);
    const float cm = fg * c + ig * inn;
    const float og = sigmoidf_(owcp[q] * cm + zop[q] + obp[q]);
    cmp[q] = cm;
    hp[q] = og * tanhf_(cm);
  }
  *(float4*)(out + (size_t)b * OUT_F + j) = cm4;
  *(float4*)(out + (size_t)BATCH * OUT_F + (size_t)b * OUT_F + j) = h4;
}

// ---------------------------------------------------------------------------
extern "C" void kernel_launch(void* const* d_in, const int* in_sizes, int n_in,
                              void* d_out, int out_size, void* d_ws, size_t ws_size,
                              hipStream_t stream) {
  const float* x       = (const float*)d_in[0];
  const float* C       = (const float*)d_in[1];
  const float* H       = (const float*)d_in[2];
  const float* fg_w_c  = (const float*)d_in[3];
  const float* fg_w_h  = (const float*)d_in[4];
  const float* fg_w_x  = (const float*)d_in[5];
  const float* fg_b    = (const float*)d_in[6];
  const float* ig_w_c  = (const float*)d_in[7];
  const float* ig_w_h  = (const float*)d_in[8];
  const float* ig_w_x  = (const float*)d_in[9];
  const float* ig_b    = (const float*)d_in[10];
  const float* in_w_h  = (const float*)d_in[11];
  const float* in_w_x  = (const float*)d_in[12];
  const float* in_b    = (const float*)d_in[13];
  const float* og_w_cn = (const float*)d_in[14];
  const float* og_w_h  = (const float*)d_in[15];
  const float* og_w_x  = (const float*)d_in[16];
  const float* og_b    = (const float*)d_in[17];
  const int*   nptr    = (const int*)d_in[18];

  // workspace layout (16B-aligned offsets)
  char* ws = (char*)d_ws;
  _Float16* Apk = (_Float16*)ws;                              // 8192*768*2  = 12,582,912 B
  _Float16* Wpk = (_Float16*)(ws + 12582912);                 // 2048*768*2  =  3,145,728 B
  float*    Z   = (float*)(ws + 15728640);                    // 8192*2048*4 = 67,108,864 B
  (void)ws_size; (void)in_sizes; (void)n_in; (void)out_size;

  pack_A<<<BATCH, 192, 0, stream>>>(H, x, nptr, Apk);
  pack_W<<<NDIM, 192, 0, stream>>>(fg_w_h, fg_w_x, ig_w_h, ig_w_x,
                                   in_w_h, in_w_x, og_w_h, og_w_x, Wpk);
  dim3 grid(NDIM / BN, BATCH / BM);  // (16, 64)
  gemm_f16<<<grid, 256, 0, stream>>>(Apk, Wpk, Z);
  epilogue<<<(BATCH * OUT_F / 4) / 256, 256, 0, stream>>>(
      Z, C, fg_w_c, fg_b, ig_w_c, ig_b, in_b, og_w_cn, og_b, (float*)d_out);
}

// Round 2
// 264.803 us; speedup vs baseline: 1.0692x; 1.0692x over previous
//
#include <hip/hip_runtime.h>

// ---------------------------------------------------------------------------
// LSTM (Alex Graves) single step, batch 8192 — fused GEMM+epilogue.
//   A = [H | x[:,n,:]]  (8192 x 768)  fp16-packed
//   W rows permuted:  row c = gate g=(c>>4)&3, unit jj=((c>>6)<<4)|(c&15)
//     -> inside a wave's 64-col tile, register j = gate, lane&15 = jj:
//        all 4 gates of one (b,jj) live in ONE lane -> epilogue in registers.
//   out[0:8192*512) = cm ; out[8192*512:) = h
// ---------------------------------------------------------------------------

typedef _Float16 half8 __attribute__((ext_vector_type(8)));
typedef _Float16 half4v __attribute__((ext_vector_type(4)));
typedef float floatx4 __attribute__((ext_vector_type(4)));

#define BATCH 8192
#define NSTEPS 16
#define IN_F 256
#define OUT_F 512
#define KDIM 768    // OUT_F + IN_F
#define NDIM 2048   // 4 * OUT_F
#define HSIZE ((size_t)BATCH * OUT_F)

#define BM 128
#define BN 128
#define BK 64

__device__ __forceinline__ void async_copy16(const void* gptr, void* lptr) {
  __builtin_amdgcn_global_load_lds(
      (const __attribute__((address_space(1))) unsigned int*)gptr,
      (__attribute__((address_space(3))) unsigned int*)lptr,
      16, 0, 0);
}

__device__ __forceinline__ float sigmoidf_(float x) {
  return 1.0f / (1.0f + __expf(-x));
}

__device__ __forceinline__ float tanhf_(float x) {
  x = fminf(fmaxf(x, -20.0f), 20.0f);   // __expf(|2x|>~176) would inf->NaN
  float e = __expf(2.0f * x);
  return (e - 1.0f) / (e + 1.0f);
}

// --------------------------- pack A = [H | x_n] ----------------------------
__global__ void pack_A(const float* __restrict__ H, const float* __restrict__ x,
                       const int* __restrict__ nptr, _Float16* __restrict__ A) {
  const int n = *nptr;
  const int b = blockIdx.x;
  const int k = threadIdx.x * 4;
  float4 v;
  if (k < OUT_F)
    v = *(const float4*)(H + (size_t)b * OUT_F + k);
  else
    v = *(const float4*)(x + ((size_t)b * NSTEPS + n) * IN_F + (k - OUT_F));
  half4v h = {(_Float16)v.x, (_Float16)v.y, (_Float16)v.z, (_Float16)v.w};
  *(half4v*)(A + (size_t)b * KDIM + k) = h;
}

// ------------------------ pack W (2048 x 768 fp16) -------------------------
// Permuted rows: c -> gate g=(c>>4)&3, unit jj=((c>>6)<<4)|(c&15).
// cols [0,512)=w_h row jj of gate g ; [512,768)=w_x row jj.
__global__ void pack_W(const float* __restrict__ fg_w_h, const float* __restrict__ fg_w_x,
                       const float* __restrict__ ig_w_h, const float* __restrict__ ig_w_x,
                       const float* __restrict__ in_w_h, const float* __restrict__ in_w_x,
                       const float* __restrict__ og_w_h, const float* __restrict__ og_w_x,
                       _Float16* __restrict__ W) {
  const int row = blockIdx.x;
  const int g  = (row >> 4) & 3;
  const int jj = ((row >> 6) << 4) | (row & 15);
  const int k = threadIdx.x * 4;
  const float* src;
  if (k < OUT_F) {
    const float* wh = (g == 0) ? fg_w_h : (g == 1) ? ig_w_h : (g == 2) ? in_w_h : og_w_h;
    src = wh + (size_t)jj * OUT_F + k;
  } else {
    const float* wx = (g == 0) ? fg_w_x : (g == 1) ? ig_w_x : (g == 2) ? in_w_x : og_w_x;
    src = wx + (size_t)jj * IN_F + (k - OUT_F);
  }
  float4 v = *(const float4*)src;
  half4v h = {(_Float16)v.x, (_Float16)v.y, (_Float16)v.z, (_Float16)v.w};
  *(half4v*)(W + (size_t)row * KDIM + k) = h;
}

// ---------------------- fused GEMM + gate epilogue -------------------------
// 128x128 tile, BK=64, 256 thr / 4 waves, each wave 64x64 (4x4 MFMA tiles).
// LDS 16B-granule XOR swizzle applied on the GLOBAL address side (keeps
// global_load_lds's wave-uniform-base+lane*16 rule; ds_read_b128 2-way free).
__global__ __launch_bounds__(256) void gemm_lstm(
    const _Float16* __restrict__ A, const _Float16* __restrict__ W,
    const float* __restrict__ C,
    const float* __restrict__ fg_w_c, const float* __restrict__ fg_b,
    const float* __restrict__ ig_w_c, const float* __restrict__ ig_b,
    const float* __restrict__ in_b,
    const float* __restrict__ og_w_cn, const float* __restrict__ og_b,
    float* __restrict__ out) {
  __shared__ __align__(16) _Float16 As[BM * BK];
  __shared__ __align__(16) _Float16 Bs[BN * BK];

  const int tid = threadIdx.x;
  const int lane = tid & 63;
  const int wave = tid >> 6;
  const int quad = lane >> 4;
  const int l16 = lane & 15;
  const int m0 = blockIdx.y * BM;
  const int n0 = blockIdx.x * BN;
  const int mw = (wave >> 1) * 64;
  const int nw = (wave & 1) * 64;

  // this lane's output unit (fixed: all 4 j-tiles of the wave share one jj set)
  const int jj = (((n0 + nw) >> 6) << 4) | l16;
  const float fwc = fg_w_c[jj], fb = fg_b[jj];
  const float iwc = ig_w_c[jj], ib = ig_b[jj];
  const float nb  = in_b[jj];
  const float owc = og_w_cn[jj], ob = og_b[jj];

  floatx4 acc[4][4] = {};

  for (int kt = 0; kt < KDIM; kt += BK) {
    __syncthreads();
#pragma unroll
    for (int r = 0; r < 4; ++r) {
      const int g = r * 256 + tid;       // 16B granule index
      const int row = g >> 3;
      const int cl = g & 7;
      const int cg = cl ^ (row & 7);     // swizzled global chunk
      async_copy16(A + (size_t)(m0 + row) * KDIM + kt + cg * 8,
                   (_Float16*)As + g * 8);
      async_copy16(W + (size_t)(n0 + row) * KDIM + kt + cg * 8,
                   (_Float16*)Bs + g * 8);
    }
    __syncthreads();

#pragma unroll
    for (int ks = 0; ks < 2; ++ks) {
      half8 af[4], bf[4];
#pragma unroll
      for (int i = 0; i < 4; ++i) {
        const int row = mw + i * 16 + l16;
        const int chunk = ks * 4 + quad;
        const int gran = row * 8 + (chunk ^ (row & 7));
        af[i] = *(const half8*)(As + gran * 8);
      }
#pragma unroll
      for (int j = 0; j < 4; ++j) {
        const int row = nw + j * 16 + l16;
        const int chunk = ks * 4 + quad;
        const int gran = row * 8 + (chunk ^ (row & 7));
        bf[j] = *(const half8*)(Bs + gran * 8);
      }
#pragma unroll
      for (int i = 0; i < 4; ++i)
#pragma unroll
        for (int j = 0; j < 4; ++j)
          acc[i][j] = __builtin_amdgcn_mfma_f32_16x16x32_f16(af[i], bf[j], acc[i][j], 0, 0, 0);
    }
  }

  // Epilogue in registers. C/D layout: col=lane&15 (=jj lane), row=quad*4+r.
  // acc[i][j][r] = gate-j pre-activation (minus w_c*C and bias) for
  // b = m0+mw+i*16+quad*4+r, unit jj.
#pragma unroll
  for (int i = 0; i < 4; ++i) {
    const int rbase = m0 + mw + i * 16 + quad * 4;
#pragma unroll
    for (int r = 0; r < 4; ++r) {
      const int b = rbase + r;
      const float c = C[(size_t)b * OUT_F + jj];
      const float fg  = sigmoidf_(fwc * c + acc[i][0][r] + fb);
      const float ig  = sigmoidf_(iwc * c + acc[i][1][r] + ib);
      const float inn = tanhf_(acc[i][2][r] + nb);
      const float cm  = fg * c + ig * inn;
      const float og  = sigmoidf_(owc * cm + acc[i][3][r] + ob);
      out[(size_t)b * OUT_F + jj] = cm;
      out[HSIZE + (size_t)b * OUT_F + jj] = og * tanhf_(cm);
    }
  }
}

// ---------------------------------------------------------------------------
extern "C" void kernel_launch(void* const* d_in, const int* in_sizes, int n_in,
                              void* d_out, int out_size, void* d_ws, size_t ws_size,
                              hipStream_t stream) {
  const float* x       = (const float*)d_in[0];
  const float* C       = (const float*)d_in[1];
  const float* H       = (const float*)d_in[2];
  const float* fg_w_c  = (const float*)d_in[3];
  const float* fg_w_h  = (const float*)d_in[4];
  const float* fg_w_x  = (const float*)d_in[5];
  const float* fg_b    = (const float*)d_in[6];
  const float* ig_w_c  = (const float*)d_in[7];
  const float* ig_w_h  = (const float*)d_in[8];
  const float* ig_w_x  = (const float*)d_in[9];
  const float* ig_b    = (const float*)d_in[10];
  const float* in_w_h  = (const float*)d_in[11];
  const float* in_w_x  = (const float*)d_in[12];
  const float* in_b    = (const float*)d_in[13];
  const float* og_w_cn = (const float*)d_in[14];
  const float* og_w_h  = (const float*)d_in[15];
  const float* og_w_x  = (const float*)d_in[16];
  const float* og_b    = (const float*)d_in[17];
  const int*   nptr    = (const int*)d_in[18];

  char* ws = (char*)d_ws;
  _Float16* Apk = (_Float16*)ws;                // 8192*768*2 = 12,582,912 B
  _Float16* Wpk = (_Float16*)(ws + 12582912);   // 2048*768*2 =  3,145,728 B
  (void)ws_size; (void)in_sizes; (void)n_in; (void)out_size;

  pack_A<<<BATCH, 192, 0, stream>>>(H, x, nptr, Apk);
  pack_W<<<NDIM, 192, 0, stream>>>(fg_w_h, fg_w_x, ig_w_h, ig_w_x,
                                   in_w_h, in_w_x, og_w_h, og_w_x, Wpk);
  dim3 grid(NDIM / BN, BATCH / BM);  // (16, 64)
  gemm_lstm<<<grid, 256, 0, stream>>>(Apk, Wpk, C,
                                      fg_w_c, fg_b, ig_w_c, ig_b, in_b,
                                      og_w_cn, og_b, (float*)d_out);
}

// Round 3
// 259.190 us; speedup vs baseline: 1.0923x; 1.0217x over previous
//
#include <hip/hip_runtime.h>

// ---------------------------------------------------------------------------
// LSTM (Alex Graves) single step, batch 8192 — fused GEMM+epilogue, r3.
//   A = [H | x[:,n,:]]  (8192 x 768)  fp16-packed
//   W rows permuted:  row c = gate g=(c>>4)&3, unit jj=((c>>6)<<4)|(c&15)
//     -> inside a wave's 64-col tile, register j = gate, lane&15 = jj:
//        all 4 gates of one (b,jj) live in ONE lane -> epilogue in registers.
//   r3: __launch_bounds__(256,4) to hold VGPR<=128 (4 blocks/CU, grid is
//       exactly 4/CU), C loads batched before tanh(inn) to hide tail latency,
//       pack_A+pack_W merged into one dispatch.
//   out[0:8192*512) = cm ; out[8192*512:) = h
// ---------------------------------------------------------------------------

typedef _Float16 half8 __attribute__((ext_vector_type(8)));
typedef _Float16 half4v __attribute__((ext_vector_type(4)));
typedef float floatx4 __attribute__((ext_vector_type(4)));

#define BATCH 8192
#define NSTEPS 16
#define IN_F 256
#define OUT_F 512
#define KDIM 768    // OUT_F + IN_F
#define NDIM 2048   // 4 * OUT_F
#define HSIZE ((size_t)BATCH * OUT_F)

#define BM 128
#define BN 128
#define BK 64

__device__ __forceinline__ void async_copy16(const void* gptr, void* lptr) {
  __builtin_amdgcn_global_load_lds(
      (const __attribute__((address_space(1))) unsigned int*)gptr,
      (__attribute__((address_space(3))) unsigned int*)lptr,
      16, 0, 0);
}

__device__ __forceinline__ float sigmoidf_(float x) {
  return 1.0f / (1.0f + __expf(-x));
}

__device__ __forceinline__ float tanhf_(float x) {
  x = fminf(fmaxf(x, -20.0f), 20.0f);   // __expf(|2x|>~176) would inf->NaN
  float e = __expf(2.0f * x);
  return (e - 1.0f) / (e + 1.0f);
}

// ------------------- merged pack: A rows then W rows -----------------------
// blocks [0,8192): A row b = [H[b] | x[b,n]] ; blocks [8192,10240): W row.
// W permuted rows: c -> gate g=(c>>4)&3, unit jj=((c>>6)<<4)|(c&15);
// cols [0,512)=w_h row jj of gate g ; [512,768)=w_x row jj.
__global__ void pack_AW(const float* __restrict__ H, const float* __restrict__ x,
                        const int* __restrict__ nptr,
                        const float* __restrict__ fg_w_h, const float* __restrict__ fg_w_x,
                        const float* __restrict__ ig_w_h, const float* __restrict__ ig_w_x,
                        const float* __restrict__ in_w_h, const float* __restrict__ in_w_x,
                        const float* __restrict__ og_w_h, const float* __restrict__ og_w_x,
                        _Float16* __restrict__ A, _Float16* __restrict__ W) {
  const int blk = blockIdx.x;
  const int k = threadIdx.x * 4;
  const float* src;
  _Float16* dst;
  if (blk < BATCH) {
    const int b = blk;
    if (k < OUT_F) {
      src = H + (size_t)b * OUT_F + k;
    } else {
      const int n = *nptr;
      src = x + ((size_t)b * NSTEPS + n) * IN_F + (k - OUT_F);
    }
    dst = A + (size_t)b * KDIM + k;
  } else {
    const int row = blk - BATCH;
    const int g  = (row >> 4) & 3;
    const int jj = ((row >> 6) << 4) | (row & 15);
    if (k < OUT_F) {
      const float* wh = (g == 0) ? fg_w_h : (g == 1) ? ig_w_h : (g == 2) ? in_w_h : og_w_h;
      src = wh + (size_t)jj * OUT_F + k;
    } else {
      const float* wx = (g == 0) ? fg_w_x : (g == 1) ? ig_w_x : (g == 2) ? in_w_x : og_w_x;
      src = wx + (size_t)jj * IN_F + (k - OUT_F);
    }
    dst = W + (size_t)row * KDIM + k;
  }
  float4 v = *(const float4*)src;
  half4v h = {(_Float16)v.x, (_Float16)v.y, (_Float16)v.z, (_Float16)v.w};
  *(half4v*)dst = h;
}

// ---------------------- fused GEMM + gate epilogue -------------------------
// 128x128 tile, BK=64, 256 thr / 4 waves, each wave 64x64 (4x4 MFMA tiles).
// LDS 16B-granule XOR swizzle applied on the GLOBAL address side (keeps
// global_load_lds's wave-uniform-base+lane*16 rule; ds_read_b128 2-way free).
// __launch_bounds__(256,4): 4 waves/EU -> <=128 VGPR -> 4 blocks/CU resident
// (grid = 1024 = exactly 4/CU; at 3 resident the grid drains unevenly).
__global__ __launch_bounds__(256, 4) void gemm_lstm(
    const _Float16* __restrict__ A, const _Float16* __restrict__ W,
    const float* __restrict__ C,
    const float* __restrict__ fg_w_c, const float* __restrict__ fg_b,
    const float* __restrict__ ig_w_c, const float* __restrict__ ig_b,
    const float* __restrict__ in_b,
    const float* __restrict__ og_w_cn, const float* __restrict__ og_b,
    float* __restrict__ out) {
  __shared__ __align__(16) _Float16 As[BM * BK];
  __shared__ __align__(16) _Float16 Bs[BN * BK];

  const int tid = threadIdx.x;
  const int lane = tid & 63;
  const int wave = tid >> 6;
  const int quad = lane >> 4;
  const int l16 = lane & 15;
  const int m0 = blockIdx.y * BM;
  const int n0 = blockIdx.x * BN;
  const int mw = (wave >> 1) * 64;
  const int nw = (wave & 1) * 64;

  // this lane's output unit (all 4 j-tiles of the wave share one jj set)
  const int jj = (((n0 + nw) >> 6) << 4) | l16;
  const float fwc = fg_w_c[jj], fb = fg_b[jj];
  const float iwc = ig_w_c[jj], ib = ig_b[jj];
  const float nb  = in_b[jj];
  const float owc = og_w_cn[jj], ob = og_b[jj];

  floatx4 acc[4][4] = {};

  for (int kt = 0; kt < KDIM; kt += BK) {
    __syncthreads();
#pragma unroll
    for (int r = 0; r < 4; ++r) {
      const int g = r * 256 + tid;       // 16B granule index
      const int row = g >> 3;
      const int cl = g & 7;
      const int cg = cl ^ (row & 7);     // swizzled global chunk
      async_copy16(A + (size_t)(m0 + row) * KDIM + kt + cg * 8,
                   (_Float16*)As + g * 8);
      async_copy16(W + (size_t)(n0 + row) * KDIM + kt + cg * 8,
                   (_Float16*)Bs + g * 8);
    }
    __syncthreads();

#pragma unroll
    for (int ks = 0; ks < 2; ++ks) {
      half8 af[4], bf[4];
#pragma unroll
      for (int i = 0; i < 4; ++i) {
        const int row = mw + i * 16 + l16;
        const int chunk = ks * 4 + quad;
        const int gran = row * 8 + (chunk ^ (row & 7));
        af[i] = *(const half8*)(As + gran * 8);
      }
#pragma unroll
      for (int j = 0; j < 4; ++j) {
        const int row = nw + j * 16 + l16;
        const int chunk = ks * 4 + quad;
        const int gran = row * 8 + (chunk ^ (row & 7));
        bf[j] = *(const half8*)(Bs + gran * 8);
      }
#pragma unroll
      for (int i = 0; i < 4; ++i)
#pragma unroll
        for (int j = 0; j < 4; ++j)
          acc[i][j] = __builtin_amdgcn_mfma_f32_16x16x32_f16(af[i], bf[j], acc[i][j], 0, 0, 0);
    }
  }

  // ---- epilogue in registers. C/D layout: col=lane&15, row=quad*4+r ----
  // Batch the 16 cold C loads first, then compute the C-independent tanh(inn)
  // while they're in flight (hides ~900cyc HBM latency behind transcendentals).
  float cv[16];
#pragma unroll
  for (int i = 0; i < 4; ++i) {
    const int rbase = m0 + mw + i * 16 + quad * 4;
#pragma unroll
    for (int r = 0; r < 4; ++r)
      cv[i * 4 + r] = C[(size_t)(rbase + r) * OUT_F + jj];
  }
  float inn[16];
#pragma unroll
  for (int i = 0; i < 4; ++i)
#pragma unroll
    for (int r = 0; r < 4; ++r)
      inn[i * 4 + r] = tanhf_(acc[i][2][r] + nb);
#pragma unroll
  for (int i = 0; i < 4; ++i) {
    const int rbase = m0 + mw + i * 16 + quad * 4;
#pragma unroll
    for (int r = 0; r < 4; ++r) {
      const int b = rbase + r;
      const float c = cv[i * 4 + r];
      const float fg  = sigmoidf_(fwc * c + acc[i][0][r] + fb);
      const float ig  = sigmoidf_(iwc * c + acc[i][1][r] + ib);
      const float cm  = fg * c + ig * inn[i * 4 + r];
      const float og  = sigmoidf_(owc * cm + acc[i][3][r] + ob);
      out[(size_t)b * OUT_F + jj] = cm;
      out[HSIZE + (size_t)b * OUT_F + jj] = og * tanhf_(cm);
    }
  }
}

// ---------------------------------------------------------------------------
extern "C" void kernel_launch(void* const* d_in, const int* in_sizes, int n_in,
                              void* d_out, int out_size, void* d_ws, size_t ws_size,
                              hipStream_t stream) {
  const float* x       = (const float*)d_in[0];
  const float* C       = (const float*)d_in[1];
  const float* H       = (const float*)d_in[2];
  const float* fg_w_c  = (const float*)d_in[3];
  const float* fg_w_h  = (const float*)d_in[4];
  const float* fg_w_x  = (const float*)d_in[5];
  const float* fg_b    = (const float*)d_in[6];
  const float* ig_w_c  = (const float*)d_in[7];
  const float* ig_w_h  = (const float*)d_in[8];
  const float* ig_w_x  = (const float*)d_in[9];
  const float* ig_b    = (const float*)d_in[10];
  const float* in_w_h  = (const float*)d_in[11];
  const float* in_w_x  = (const float*)d_in[12];
  const float* in_b    = (const float*)d_in[13];
  const float* og_w_cn = (const float*)d_in[14];
  const float* og_w_h  = (const float*)d_in[15];
  const float* og_w_x  = (const float*)d_in[16];
  const float* og_b    = (const float*)d_in[17];
  const int*   nptr    = (const int*)d_in[18];

  char* ws = (char*)d_ws;
  _Float16* Apk = (_Float16*)ws;                // 8192*768*2 = 12,582,912 B
  _Float16* Wpk = (_Float16*)(ws + 12582912);   // 2048*768*2 =  3,145,728 B
  (void)ws_size; (void)in_sizes; (void)n_in; (void)out_size;

  pack_AW<<<BATCH + NDIM, 192, 0, stream>>>(H, x, nptr,
                                            fg_w_h, fg_w_x, ig_w_h, ig_w_x,
                                            in_w_h, in_w_x, og_w_h, og_w_x,
                                            Apk, Wpk);
  dim3 grid(NDIM / BN, BATCH / BM);  // (16, 64) = 1024 blocks = 4/CU
  gemm_lstm<<<grid, 256, 0, stream>>>(Apk, Wpk, C,
                                      fg_w_c, fg_b, ig_w_c, ig_b, in_b,
                                      og_w_cn, og_b, (float*)d_out);
}